// Round 8
// baseline (294.559 us; speedup 1.0000x reference)
//
#include <hip/hip_runtime.h>

#define HH 256
#define WW 256
#define PAD 4
#define HW (HH * WW)

#define TW 32      // tile width (pixels)
#define TH 8       // tile height (pixels)
#define PR 16      // patch rows = TH + 8
#define PC 40      // patch cols = TW + 8
#define PCP 41     // padded LDS col stride (proven conflict-free in r4/r6)
#define NSPLIT 4   // channel splits across blocks
#define CPB 64     // channels per block
#define NG 16      // channel groups of 4 per block
#define NSLOT 3    // ceil(PR*PC / 256) staging slots per thread

__device__ __forceinline__ void fma4(float4& a, const float4& k, float w) {
    a.x = fmaf(k.x, w, a.x);
    a.y = fmaf(k.y, w, a.y);
    a.z = fmaf(k.z, w, a.z);
    a.w = fmaf(k.w, w, a.w);
}

// Accumulate taps t in [LO,HI) for both owned pixels. All indices compile-time
// after unroll; wt arrays stay register-resident.
template<int LO, int HI>
__device__ __forceinline__ void compute_taps(const float4* __restrict__ bp,
                                             const float (&wt0)[41], const float (&wt1)[41],
                                             float4& a0, float4& a1) {
    #pragma unroll
    for (int r = 0; r < 9; ++r) {
        #pragma unroll
        for (int c = 0; c < 10; ++c) {
            constexpr int dummy = 0; (void)dummy;
            const int t0 = r * 9 + c;       // tap feeding a0 (needs c<9)
            const int t1 = r * 9 + c - 1;   // tap feeding a1 (needs c>=1)
            const bool u0 = (c < 9) && (t0 >= LO) && (t0 < HI);
            const bool u1 = (c >= 1) && (t1 >= LO) && (t1 < HI);
            if (u0 || u1) {
                float4 k4 = bp[r * PCP + c];           // ds_read_b128, imm offset
                if (u0) fma4(a0, k4, wt0[t0 - LO]);
                if (u1) fma4(a1, k4, wt1[t1 - LO]);
            }
        }
    }
}

__global__ __launch_bounds__(256, 4)
void prop_kernel(const float* __restrict__ key, const float* __restrict__ wts,
                 float* __restrict__ out) {
    // double-buffered key patch: [buf][row*PCP+col] of float4 (4 channels)
    __shared__ float4 smem[2][PR * PCP];
    // role-B partial sums: pair q uses cells {3q, 3q+1}; stride 3 cells = 12
    // dwords -> 8 distinct start banks across lanes (conflict-minimal)
    __shared__ float4 red[128 * 3];

    const int tid   = threadIdx.x;
    const bool roleA = tid < 128;
    const int q    = tid & 127;  // pixel-pair index
    const int tw   = q & 15;     // w-pair 0..15
    const int th   = q >> 4;     // h 0..7
    const int w0   = blockIdx.x * TW;
    const int h0   = blockIdx.y * TH;
    const int c0   = blockIdx.z * CPB;
    const int h    = h0 + th;
    const int w    = w0 + 2 * tw;

    // ---- per-pixel weights: A holds taps 0..40, B holds 41..80 ----
    float wt0[41], wt1[41];
    {
        const int lo  = roleA ? 0 : 41;
        const int cnt = roleA ? 41 : 40;
        const float* wp = wts + (size_t)lo * HW + h * WW + w;  // w even -> 8B aligned
        #pragma unroll
        for (int t = 0; t < 41; ++t) {
            if (t < cnt) {
                float2 v = *reinterpret_cast<const float2*>(wp + (size_t)t * HW);
                wt0[t] = v.x;
                wt1[t] = v.y;
            }
        }
    }

    // ---- hoisted staging state (computed ONCE) ----
    const float* sp[NSLOT];
    int  sdst[NSLOT];
    bool sin_[NSLOT];
    bool sact[NSLOT];
    #pragma unroll
    for (int k = 0; k < NSLOT; ++k) {
        int p   = tid + k * 256;
        bool act = p < PR * PC;
        int row = p / PC;
        int col = p - row * PC;
        int gh  = h0 - PAD + row;
        int gw  = w0 - PAD + col;
        bool inb = act && (unsigned)gh < HH && (unsigned)gw < WW;
        sact[k] = act;
        sin_[k] = inb;
        sdst[k] = row * PCP + col;
        sp[k]   = key + (size_t)c0 * HW + (inb ? (gh * WW + gw) : 0);
    }

    // ---- prologue: stage channel-group 0 into buffer 0 ----
    {
        float4 v[NSLOT];
        #pragma unroll
        for (int k = 0; k < NSLOT; ++k) {
            const float* qp = sp[k];
            v[k].x = qp[0];
            v[k].y = qp[HW];
            v[k].z = qp[2 * HW];
            v[k].w = qp[3 * HW];
            if (!sin_[k]) v[k] = make_float4(0.f, 0.f, 0.f, 0.f);
            sp[k] += 4 * HW;
        }
        #pragma unroll
        for (int k = 0; k < NSLOT; ++k)
            if (sact[k]) smem[0][sdst[k]] = v[k];
    }
    __syncthreads();

    float* op = out + (size_t)c0 * HW + h * WW + w;

    for (int g = 0; g < NG; ++g) {
        const bool pf = (g + 1 < NG);

        // 1) issue next-group staging loads into REGISTERS
        float4 stg[NSLOT];
        if (pf) {
            #pragma unroll
            for (int k = 0; k < NSLOT; ++k) {
                const float* qp = sp[k];
                stg[k].x = qp[0];
                stg[k].y = qp[HW];
                stg[k].z = qp[2 * HW];
                stg[k].w = qp[3 * HW];
                if (!sin_[k]) stg[k] = make_float4(0.f, 0.f, 0.f, 0.f);
                sp[k] += 4 * HW;
            }
        }

        // 2) compute role's tap-partials for 2 px x 4 ch
        const float4* bp = &smem[g & 1][th * PCP + 2 * tw];
        float4 a0 = make_float4(0.f, 0.f, 0.f, 0.f);
        float4 a1 = make_float4(0.f, 0.f, 0.f, 0.f);
        if (roleA) compute_taps<0, 41>(bp, wt0, wt1, a0, a1);
        else       compute_taps<41, 81>(bp, wt0, wt1, a0, a1);

        // 3) B posts partials
        if (!roleA) {
            red[q * 3]     = a0;
            red[q * 3 + 1] = a1;
        }
        __syncthreads();   // red ready; all reads of smem[g&1] done

        // 4) A combines and stores 2 px x 4 ch
        if (roleA) {
            float4 b0 = red[q * 3];
            float4 b1 = red[q * 3 + 1];
            a0.x += b0.x; a0.y += b0.y; a0.z += b0.z; a0.w += b0.w;
            a1.x += b1.x; a1.y += b1.y; a1.z += b1.z; a1.w += b1.w;
            *reinterpret_cast<float2*>(op)          = make_float2(a0.x, a1.x);
            *reinterpret_cast<float2*>(op + HW)     = make_float2(a0.y, a1.y);
            *reinterpret_cast<float2*>(op + 2 * HW) = make_float2(a0.z, a1.z);
            *reinterpret_cast<float2*>(op + 3 * HW) = make_float2(a0.w, a1.w);
        }
        op += 4 * HW;

        // 5) write staged regs to the other buffer
        if (pf) {
            #pragma unroll
            for (int k = 0; k < NSLOT; ++k)
                if (sact[k]) smem[(g + 1) & 1][sdst[k]] = stg[k];
        }

        // 6) barrier: next buffer ready; red consumed (A read before here)
        __syncthreads();
    }
}

extern "C" void kernel_launch(void* const* d_in, const int* in_sizes, int n_in,
                              void* d_out, int out_size, void* d_ws, size_t ws_size,
                              hipStream_t stream) {
    const float* key = (const float*)d_in[0];   // (1,256,256,256) f32
    const float* wts = (const float*)d_in[1];   // (1,81,256,256)  f32
    float* out = (float*)d_out;                 // (1,256,256,256) f32

    dim3 grid(WW / TW, HH / TH, NSPLIT);        // 8 x 32 x 4 = 1024 blocks (4/CU)
    prop_kernel<<<grid, 256, 0, stream>>>(key, wts, out);
}